// Round 11
// baseline (168.481 us; speedup 1.0000x reference)
//
#include <hip/hip_runtime.h>
#include <math.h>

#define B_    32
#define H_    512
#define W_    512
#define NBINS 256
#define NT    254
#define HW_   (H_ * W_)

// ws layout — every slot written unconditionally this launch; readers are in
// LATER dispatches only (kernel boundary = coherence). No memset, no flags.
//   [0       .. 1048576)  int   hist_p[1024][256]   per-block Otsu-hist partial
//   [1048576 .. 2097152)  int   g0_p[1024][256]     per-block q-bucket count
//   [2097152 .. 3145728)  float g1_p[1024][256]     per-block q-bucket sum-p
//   [3145728 .. 3149824)  float p2_p[1024]          per-block sum p^2
//   [3149824 .. 3149952)  float lp[32]              per-batch loss
//   [3149952 .. 3150080)  float totf[32]            per-batch mask count
#define WS_NEED 3150080

__device__ __forceinline__ float max5(float a, float b, float c, float d, float e) {
    return fmaxf(fmaxf(fmaxf(a, b), fmaxf(c, d)), e);
}
__device__ __forceinline__ float4 fmax4(float4 a, float4 b) {
    return make_float4(fmaxf(a.x, b.x), fmaxf(a.y, b.y),
                       fmaxf(a.z, b.z), fmaxf(a.w, b.w));
}
__device__ __forceinline__ int bin_of(float im) {
    float v = im * 255.0f;                  // reference: v = imgs*255
    float u = v * (256.0f / 255.0f);        // reference: v*(NBINS/255.0) in f32
    int bin = (int)floorf(u);
    return bin < 0 ? 0 : (bin > NBINS - 1 ? NBINS - 1 : bin);
}

// Dilated-mask (5x5 max > 0) for 4 rows x 8 cols. Validated R7-R9.
__device__ __forceinline__ void dilate4(const float* __restrict__ lab,
                                        int rbase, int c0, int lane,
                                        unsigned mrow[4]) {
    float4 A[4], Bq[4];
#pragma unroll
    for (int r = 0; r < 4; ++r) {
        A[r]  = make_float4(0.f, 0.f, 0.f, 0.f);
        Bq[r] = A[r];
    }
#pragma unroll
    for (int k = 0; k < 8; ++k) {
        int gr = rbase - 2 + k;
        float4 la = make_float4(0.f, 0.f, 0.f, 0.f), lb = la;
        if ((unsigned)gr < (unsigned)H_) {
            la = *(const float4*)(lab + gr * W_ + c0);
            lb = *(const float4*)(lab + gr * W_ + c0 + 4);
        }
#pragma unroll
        for (int r = 0; r < 4; ++r)
            if (k >= r && k <= r + 4) { A[r] = fmax4(A[r], la); Bq[r] = fmax4(Bq[r], lb); }
    }
#pragma unroll
    for (int r = 0; r < 4; ++r) {
        float l2 = __shfl_up(Bq[r].z, 1);
        float l1 = __shfl_up(Bq[r].w, 1);
        float r1 = __shfl_down(A[r].x, 1);
        float r2 = __shfl_down(A[r].y, 1);
        if (lane == 0)  { l1 = 0.f; l2 = 0.f; }
        if (lane == 63) { r1 = 0.f; r2 = 0.f; }
        float e[12] = { l2, l1, A[r].x, A[r].y, A[r].z, A[r].w,
                        Bq[r].x, Bq[r].y, Bq[r].z, Bq[r].w, r1, r2 };
        unsigned m = 0;
#pragma unroll
        for (int c = 0; c < 8; ++c)
            if (max5(e[c], e[c+1], e[c+2], e[c+3], e[c+4]) > 0.f) m |= 1u << c;
        mrow[r] = m;
    }
}

// Per-pixel accumulate (validated R5-R10): Otsu hist + exact q-bucket + sum p^2.
__device__ __forceinline__ void px_acc(unsigned m, unsigned bit, float im, float p,
                                       int* s_hist, int* s_g0, float* s_g1,
                                       const float* s_thr, float& p2a) {
    if (m & bit) {
        atomicAdd(&s_hist[bin_of(im)], 1);
        int q0 = (int)(im * 255.0f);
        if (q0 > 254) q0 = 254;
        int q = q0;
        if (q0 < 254 && im >= s_thr[q0 + 1]) q = q0 + 1;
        else if (q0 > 0 && im < s_thr[q0])   q = q0 - 1;
        atomicAdd(&s_g0[q], 1);
        atomicAdd(&s_g1[q], p);
        p2a += p * p;
    }
}

// ---------------------------------------------------------------------------
// Kernel 1: dense single pass (R8 best config). Grid (32 bands x 32 batches)
// = 1024 blocks, 16 rows/block, 4 rows/wave via dilate4. Plain stores only.
// ---------------------------------------------------------------------------
__global__ __launch_bounds__(256, 4) void k_main_p(const float* __restrict__ labels,
                                                   const float* __restrict__ images,
                                                   const float* __restrict__ preds,
                                                   int* __restrict__ hist_p,
                                                   int* __restrict__ g0_p,
                                                   float* __restrict__ g1_p,
                                                   float* __restrict__ p2_p) {
    __shared__ int   s_hist[NBINS];
    __shared__ int   s_g0[NBINS];
    __shared__ float s_g1[NBINS];
    __shared__ float s_thr[NBINS];
    __shared__ float s_red[256];

    const int tid   = threadIdx.x;
    const int lane  = tid & 63;
    const int w     = tid >> 6;
    const int band  = blockIdx.x;           // 0..31 (16-row bands)
    const int b     = blockIdx.y;           // 0..31
    const int slot  = b * 32 + band;
    const int rbase = band * 16 + w * 4;
    const int c0    = lane * 8;
    const float* lab = labels + (size_t)b * HW_;
    const float* img = images + (size_t)b * HW_;
    const float* prd = preds  + (size_t)b * HW_;

    s_hist[tid] = 0;
    s_g0[tid]   = 0;
    s_g1[tid]   = 0.0f;
    s_thr[tid]  = (float)tid / 255.0f;
    __syncthreads();

    unsigned mrow[4];
    dilate4(lab, rbase, c0, lane, mrow);

    float p2a = 0.0f;
#pragma unroll
    for (int r = 0; r < 4; ++r) {
        unsigned m = mrow[r];
        size_t off = (size_t)(rbase + r) * W_ + c0;
        // dense unconditional loads (sparse-load MLP collapse measured R4)
        float4 iv0 = *(const float4*)(img + off);
        float4 iv1 = *(const float4*)(img + off + 4);
        float4 pv0 = *(const float4*)(prd + off);
        float4 pv1 = *(const float4*)(prd + off + 4);
        px_acc(m,   1u, iv0.x, pv0.x, s_hist, s_g0, s_g1, s_thr, p2a);
        px_acc(m,   2u, iv0.y, pv0.y, s_hist, s_g0, s_g1, s_thr, p2a);
        px_acc(m,   4u, iv0.z, pv0.z, s_hist, s_g0, s_g1, s_thr, p2a);
        px_acc(m,   8u, iv0.w, pv0.w, s_hist, s_g0, s_g1, s_thr, p2a);
        px_acc(m,  16u, iv1.x, pv1.x, s_hist, s_g0, s_g1, s_thr, p2a);
        px_acc(m,  32u, iv1.y, pv1.y, s_hist, s_g0, s_g1, s_thr, p2a);
        px_acc(m,  64u, iv1.z, pv1.z, s_hist, s_g0, s_g1, s_thr, p2a);
        px_acc(m, 128u, iv1.w, pv1.w, s_hist, s_g0, s_g1, s_thr, p2a);
    }

    s_red[tid] = p2a;
    __syncthreads();
    // plain stores to this block's own slot (every slot written -> poison-safe)
    hist_p[(slot << 8) + tid] = s_hist[tid];
    g0_p  [(slot << 8) + tid] = s_g0[tid];
    g1_p  [(slot << 8) + tid] = s_g1[tid];
    for (int off = 128; off > 0; off >>= 1) {
        if (tid < off) s_red[tid] += s_red[tid + off];
        __syncthreads();
    }
    if (tid == 0) p2_p[slot] = s_red[0];
}

// ---------------------------------------------------------------------------
// Kernel 2: one block per batch. Reduce 32 partials, bit-exact Otsu argmax
// (full 254x254, thread tid = column j), f64 suffix-sum loss. Plain stores.
// ZERO cross-block communication (stale-poll cost measured ~40us in R10).
// ---------------------------------------------------------------------------
__global__ __launch_bounds__(256) void k_search_b(const int* __restrict__ hist_p,
                                                  const int* __restrict__ g0_p,
                                                  const float* __restrict__ g1_p,
                                                  const float* __restrict__ p2_p,
                                                  float* __restrict__ lp,
                                                  float* __restrict__ totf) {
    __shared__ float  sA[NBINS];
    __shared__ float  sB[NBINS];
    __shared__ float  sPQ[NBINS][2];
    __shared__ float  sT0[NBINS];
    __shared__ float  sT2[NBINS];
    __shared__ int    s_int[256];
    __shared__ unsigned long long s_pack[256];
    __shared__ double sD0[256];
    __shared__ double sD1[256];
    __shared__ double s_res[4];
    __shared__ int    s_am;

    const int tid = threadIdx.x;
    const int b   = blockIdx.x;
    const float s = 1e-8f;

    // reduce 32 band-partials -> this batch's histogram bin `tid`
    int h = 0;
    {
        const int* hp = hist_p + ((b * 32) << 8) + tid;
#pragma unroll 8
        for (int j = 0; j < 32; ++j) h += hp[j << 8];
    }
    s_int[tid] = h;
    __syncthreads();
    for (int off = 128; off > 0; off >>= 1) {       // exact: integer counts
        if (tid < off) s_int[tid] += s_int[tid + off];
        __syncthreads();
    }
    const float ftot = (float)s_int[0];
    __syncthreads();

    float p = (float)h / ftot;
    sPQ[tid][0] = p;
    sPQ[tid][1] = p * (float)tid;
    __syncthreads();

    if (tid == 0) {                  // sequential fold == reference cumsum order
        float ch = 0.0f, cm = 0.0f;
#pragma unroll 8
        for (int i = 0; i < NBINS; ++i) {
            ch += sPQ[i][0];
            cm += sPQ[i][1];
            sA[i] = ch;
            sB[i] = cm;
        }
    }
    __syncthreads();

    const float tm = sB[NBINS - 1];
    if (tid < NT) {
        float cb = sA[tid];
        float w2 = 1.0f - cb;
        float mean2 = (tm - sB[tid]) / (w2 + s);
        float d2 = mean2 - tm;
        sT2[tid] = w2 * (d2 * d2);

        float w0 = sA[tid];
        float mean0 = sB[tid] / (w0 + s);
        float d0 = mean0 - tm;
        sT0[tid] = w0 * (d0 * d0);
    }
    __syncthreads();

    unsigned long long best = 0ull;
    if (tid < NT) {
        const float cb  = sA[tid];
        const float m1v = sB[tid];
        const float w2  = 1.0f - cb;
        const float t2v = sT2[tid];
#pragma unroll 4
        for (int i = 0; i < NT; ++i) {
            float w0 = sA[i];
            float w1 = cb - w0;
            float mean1 = (m1v - sB[i]) / (w1 + s);
            float d1 = mean1 - tm;
            float bv = (sT0[i] + w1 * (d1 * d1)) + t2v;
            bool ok = (w0 > 0.f) && (w1 > 0.f) && (w2 > 0.f);
            bv = ok ? bv : 0.0f;
            unsigned k = (unsigned)(i * NT + tid);
            // bv >= 0: float-bit order == value order; ~k => first-max tie-break
            unsigned long long pk =
                ((unsigned long long)__float_as_uint(bv) << 32) | (0xFFFFFFFFu - k);
            best = pk > best ? pk : best;
        }
    }
    s_pack[tid] = best;
    __syncthreads();
    for (int off = 128; off > 0; off >>= 1) {
        if (tid < off) {
            unsigned long long o = s_pack[tid + off];
            if (o > s_pack[tid]) s_pack[tid] = o;
        }
        __syncthreads();
    }
    if (tid == 0)
        s_am = (int)(0xFFFFFFFFu - (unsigned)(s_pack[0] & 0xFFFFFFFFull));
    __syncthreads();

    const int v  = s_am / NT + 1;           // im >= t1  <=>  q >= v
    const int wq = s_am % NT + 1;           // im >= t2  <=>  q >= wq

    // reduce g0/g1 partials for this batch
    int   gc = 0;
    float gg = 0.0f;
    {
        const int*   gp  = g0_p + ((b * 32) << 8) + tid;
        const float* gfp = g1_p + ((b * 32) << 8) + tid;
#pragma unroll 8
        for (int j = 0; j < 32; ++j) { gc += gp[j << 8]; gg += gfp[j << 8]; }
    }

    // f64 suffix sums S0/S1 at v and wq (validated R5-R10 math)
    sD0[tid] = (tid >= v) ? (double)gc : 0.0;
    sD1[tid] = (tid >= v) ? (double)gg : 0.0;
    __syncthreads();
    for (int off = 128; off > 0; off >>= 1) {
        if (tid < off) { sD0[tid] += sD0[tid + off]; sD1[tid] += sD1[tid + off]; }
        __syncthreads();
    }
    if (tid == 0) { s_res[0] = sD0[0]; s_res[1] = sD1[0]; }
    __syncthreads();

    sD0[tid] = (tid >= wq) ? (double)gc : 0.0;
    sD1[tid] = (tid >= wq) ? (double)gg : 0.0;
    __syncthreads();
    for (int off = 128; off > 0; off >>= 1) {
        if (tid < off) { sD0[tid] += sD0[tid + off]; sD1[tid] += sD1[tid + off]; }
        __syncthreads();
    }
    if (tid == 0) { s_res[2] = sD0[0]; s_res[3] = sD1[0]; }
    __syncthreads();

    // p2 partial reduce (32 values)
    sD0[tid] = (tid < 32) ? (double)p2_p[b * 32 + tid] : 0.0;
    __syncthreads();
    for (int off = 128; off > 0; off >>= 1) {
        if (tid < off) sD0[tid] += sD0[tid + off];
        __syncthreads();
    }

    if (tid == 0) {
        double S0v = s_res[0], S1v = s_res[1];
        double S0w = s_res[2], S1w = s_res[3];
        double c05 = (v <= wq) ? (S0v - S0w) : 0.0;
        double s05 = (v <= wq) ? (S1v - S1w) : 0.0;
        // sum (ci-p)^2 = |A| - 2*S1(A) + 0.25*|B\A| - S1(B\A) + sum p^2
        double sqd = S0w - 2.0 * S1w + 0.25 * c05 - s05 + sD0[0];
        float smv = ftot + 1e-8f;
        lp[b]   = (smv > 1e-8f) ? (float)sqd / smv : 0.0f;   // plain stores;
        totf[b] = ftot;                                       // next dispatch reads
    }
}

// ---------------------------------------------------------------------------
// Kernel 3: final valid-batch mean (1 block; plain loads — kernel boundary
// made k_search_b's stores visible).
// ---------------------------------------------------------------------------
__global__ __launch_bounds__(64) void k_final(const float* __restrict__ lp,
                                              const float* __restrict__ totf,
                                              float* __restrict__ out) {
    int t = threadIdx.x;
    float l = 0.0f, vc = 0.0f;
    if (t < B_) {
        float smv = totf[t] + 1e-8f;
        if (smv > 1e-8f) { l = lp[t]; vc = 1.0f; }
    }
    for (int off = 32; off > 0; off >>= 1) {
        l  += __shfl_down(l, off);
        vc += __shfl_down(vc, off);
    }
    if (t == 0) out[0] = vc > 0.0f ? l / fmaxf(vc, 1.0f) : 0.0f;
}

extern "C" void kernel_launch(void* const* d_in, const int* in_sizes, int n_in,
                              void* d_out, int out_size, void* d_ws, size_t ws_size,
                              hipStream_t stream) {
    const float* preds  = (const float*)d_in[0];
    const float* labels = (const float*)d_in[1];
    const float* images = (const float*)d_in[2];
    float* out = (float*)d_out;
    char* ws = (char*)d_ws;
    if (ws_size < (size_t)WS_NEED) return;  // harness ws is ~268 MB; never hit

    int*   hist_p = (int*)ws;
    int*   g0_p   = (int*)(ws + 1048576);
    float* g1_p   = (float*)(ws + 2097152);
    float* p2_p   = (float*)(ws + 3145728);
    float* lp     = (float*)(ws + 3149824);
    float* totf   = (float*)(ws + 3149952);

    k_main_p<<<dim3(32, B_), 256, 0, stream>>>(labels, images, preds,
                                               hist_p, g0_p, g1_p, p2_p);
    k_search_b<<<B_, 256, 0, stream>>>(hist_p, g0_p, g1_p, p2_p, lp, totf);
    k_final<<<1, 64, 0, stream>>>(lp, totf, out);
}

// Round 12
// 141.025 us; speedup vs baseline: 1.1947x; 1.1947x over previous
//
#include <hip/hip_runtime.h>
#include <math.h>

#define B_    32
#define H_    512
#define W_    512
#define NBINS 256
#define NT    254
#define HW_   (H_ * W_)

// ws layout — every slot written unconditionally this launch; readers are in
// LATER dispatches only (kernel boundary = coherence). No memset, no flags,
// no polls anywhere.
//   [0       .. 1048576)  int   hist_p[1024][256]   per-block Otsu-hist partial
//   [1048576 .. 2097152)  int   g0_p[1024][256]     per-block q-bucket count
//   [2097152 .. 3145728)  float g1_p[1024][256]     per-block q-bucket sum-p
//   [3145728 .. 3149824)  float p2_p[1024]          per-block sum p^2
//   [3149824 .. 3151872)  ull   packed_s[32][8]     per-slice argmax
//   [3151872 .. 3152000)  float totf[32]            per-batch mask count
//   [3152000 .. 3152128)  float lp[32]              per-batch loss
#define WS_NEED 3152128

__device__ __forceinline__ float max5(float a, float b, float c, float d, float e) {
    return fmaxf(fmaxf(fmaxf(a, b), fmaxf(c, d)), e);
}
__device__ __forceinline__ float4 fmax4(float4 a, float4 b) {
    return make_float4(fmaxf(a.x, b.x), fmaxf(a.y, b.y),
                       fmaxf(a.z, b.z), fmaxf(a.w, b.w));
}
__device__ __forceinline__ int bin_of(float im) {
    float v = im * 255.0f;                  // reference: v = imgs*255
    float u = v * (256.0f / 255.0f);        // reference: v*(NBINS/255.0) in f32
    int bin = (int)floorf(u);
    return bin < 0 ? 0 : (bin > NBINS - 1 ? NBINS - 1 : bin);
}

// Dilated-mask (5x5 max > 0) for 4 rows x 8 cols. Validated R7-R11.
__device__ __forceinline__ void dilate4(const float* __restrict__ lab,
                                        int rbase, int c0, int lane,
                                        unsigned mrow[4]) {
    float4 A[4], Bq[4];
#pragma unroll
    for (int r = 0; r < 4; ++r) {
        A[r]  = make_float4(0.f, 0.f, 0.f, 0.f);
        Bq[r] = A[r];
    }
#pragma unroll
    for (int k = 0; k < 8; ++k) {
        int gr = rbase - 2 + k;
        float4 la = make_float4(0.f, 0.f, 0.f, 0.f), lb = la;
        if ((unsigned)gr < (unsigned)H_) {
            la = *(const float4*)(lab + gr * W_ + c0);
            lb = *(const float4*)(lab + gr * W_ + c0 + 4);
        }
#pragma unroll
        for (int r = 0; r < 4; ++r)
            if (k >= r && k <= r + 4) { A[r] = fmax4(A[r], la); Bq[r] = fmax4(Bq[r], lb); }
    }
#pragma unroll
    for (int r = 0; r < 4; ++r) {
        float l2 = __shfl_up(Bq[r].z, 1);
        float l1 = __shfl_up(Bq[r].w, 1);
        float r1 = __shfl_down(A[r].x, 1);
        float r2 = __shfl_down(A[r].y, 1);
        if (lane == 0)  { l1 = 0.f; l2 = 0.f; }
        if (lane == 63) { r1 = 0.f; r2 = 0.f; }
        float e[12] = { l2, l1, A[r].x, A[r].y, A[r].z, A[r].w,
                        Bq[r].x, Bq[r].y, Bq[r].z, Bq[r].w, r1, r2 };
        unsigned m = 0;
#pragma unroll
        for (int c = 0; c < 8; ++c)
            if (max5(e[c], e[c+1], e[c+2], e[c+3], e[c+4]) > 0.f) m |= 1u << c;
        mrow[r] = m;
    }
}

// Per-pixel accumulate (validated R5-R11): Otsu hist + exact q-bucket + sum p^2.
__device__ __forceinline__ void px_acc(unsigned m, unsigned bit, float im, float p,
                                       int* s_hist, int* s_g0, float* s_g1,
                                       const float* s_thr, float& p2a) {
    if (m & bit) {
        atomicAdd(&s_hist[bin_of(im)], 1);
        int q0 = (int)(im * 255.0f);
        if (q0 > 254) q0 = 254;
        int q = q0;
        if (q0 < 254 && im >= s_thr[q0 + 1]) q = q0 + 1;
        else if (q0 > 0 && im < s_thr[q0])   q = q0 - 1;
        atomicAdd(&s_g0[q], 1);
        atomicAdd(&s_g1[q], p);
        p2a += p * p;
    }
}

// ---------------------------------------------------------------------------
// Kernel 1: dense single pass (R8 best config, verbatim). 1024 blocks.
// ---------------------------------------------------------------------------
__global__ __launch_bounds__(256, 4) void k_main_p(const float* __restrict__ labels,
                                                   const float* __restrict__ images,
                                                   const float* __restrict__ preds,
                                                   int* __restrict__ hist_p,
                                                   int* __restrict__ g0_p,
                                                   float* __restrict__ g1_p,
                                                   float* __restrict__ p2_p) {
    __shared__ int   s_hist[NBINS];
    __shared__ int   s_g0[NBINS];
    __shared__ float s_g1[NBINS];
    __shared__ float s_thr[NBINS];
    __shared__ float s_red[256];

    const int tid   = threadIdx.x;
    const int lane  = tid & 63;
    const int w     = tid >> 6;
    const int band  = blockIdx.x;           // 0..31 (16-row bands)
    const int b     = blockIdx.y;           // 0..31
    const int slot  = b * 32 + band;
    const int rbase = band * 16 + w * 4;
    const int c0    = lane * 8;
    const float* lab = labels + (size_t)b * HW_;
    const float* img = images + (size_t)b * HW_;
    const float* prd = preds  + (size_t)b * HW_;

    s_hist[tid] = 0;
    s_g0[tid]   = 0;
    s_g1[tid]   = 0.0f;
    s_thr[tid]  = (float)tid / 255.0f;
    __syncthreads();

    unsigned mrow[4];
    dilate4(lab, rbase, c0, lane, mrow);

    float p2a = 0.0f;
#pragma unroll
    for (int r = 0; r < 4; ++r) {
        unsigned m = mrow[r];
        size_t off = (size_t)(rbase + r) * W_ + c0;
        // dense unconditional loads (sparse-load MLP collapse measured R4)
        float4 iv0 = *(const float4*)(img + off);
        float4 iv1 = *(const float4*)(img + off + 4);
        float4 pv0 = *(const float4*)(prd + off);
        float4 pv1 = *(const float4*)(prd + off + 4);
        px_acc(m,   1u, iv0.x, pv0.x, s_hist, s_g0, s_g1, s_thr, p2a);
        px_acc(m,   2u, iv0.y, pv0.y, s_hist, s_g0, s_g1, s_thr, p2a);
        px_acc(m,   4u, iv0.z, pv0.z, s_hist, s_g0, s_g1, s_thr, p2a);
        px_acc(m,   8u, iv0.w, pv0.w, s_hist, s_g0, s_g1, s_thr, p2a);
        px_acc(m,  16u, iv1.x, pv1.x, s_hist, s_g0, s_g1, s_thr, p2a);
        px_acc(m,  32u, iv1.y, pv1.y, s_hist, s_g0, s_g1, s_thr, p2a);
        px_acc(m,  64u, iv1.z, pv1.z, s_hist, s_g0, s_g1, s_thr, p2a);
        px_acc(m, 128u, iv1.w, pv1.w, s_hist, s_g0, s_g1, s_thr, p2a);
    }

    s_red[tid] = p2a;
    __syncthreads();
    // plain stores to this block's own slot (every slot written -> poison-safe)
    hist_p[(slot << 8) + tid] = s_hist[tid];
    g0_p  [(slot << 8) + tid] = s_g0[tid];
    g1_p  [(slot << 8) + tid] = s_g1[tid];
    for (int off = 128; off > 0; off >>= 1) {
        if (tid < off) s_red[tid] += s_red[tid + off];
        __syncthreads();
    }
    if (tid == 0) p2_p[slot] = s_red[0];
}

// ---------------------------------------------------------------------------
// Kernel 2: sliced Otsu argmax, NO polls. 256 blocks = 8 i-slices x 32
// batches; 32-iter inner loop (8x shorter latency chain than R11's 254).
// Plain stores of per-slice maxima; kernel boundary publishes them.
// ---------------------------------------------------------------------------
__global__ __launch_bounds__(256) void k_search_s(const int* __restrict__ hist_p,
                                                  unsigned long long* __restrict__ packed_s,
                                                  float* __restrict__ totf) {
    __shared__ float  sA[NBINS];
    __shared__ float  sB[NBINS];
    __shared__ float  sPQ[NBINS][2];
    __shared__ float  sT0[32];
    __shared__ float  sT2[NBINS];
    __shared__ int    s_int[256];
    __shared__ unsigned long long s_pack[256];

    const int tid   = threadIdx.x;
    const int slice = blockIdx.x & 7;
    const int b     = blockIdx.x >> 3;
    const float s   = 1e-8f;

    // reduce 32 band-partials -> this batch's histogram bin `tid`
    int h = 0;
    {
        const int* hp = hist_p + ((b * 32) << 8) + tid;
#pragma unroll 8
        for (int j = 0; j < 32; ++j) h += hp[j << 8];
    }
    s_int[tid] = h;
    __syncthreads();
    for (int off = 128; off > 0; off >>= 1) {       // exact: integer counts
        if (tid < off) s_int[tid] += s_int[tid + off];
        __syncthreads();
    }
    const float ftot = (float)s_int[0];
    __syncthreads();

    float p = (float)h / ftot;
    sPQ[tid][0] = p;
    sPQ[tid][1] = p * (float)tid;
    __syncthreads();

    if (tid == 0) {                  // sequential fold == reference cumsum order
        float ch = 0.0f, cm = 0.0f;
#pragma unroll 8
        for (int i = 0; i < NBINS; ++i) {
            ch += sPQ[i][0];
            cm += sPQ[i][1];
            sA[i] = ch;
            sB[i] = cm;
        }
    }
    __syncthreads();

    const float tm = sB[NBINS - 1];
    if (tid < NT) {
        float cb = sA[tid];
        float w2 = 1.0f - cb;
        float mean2 = (tm - sB[tid]) / (w2 + s);
        float d2 = mean2 - tm;
        sT2[tid] = w2 * (d2 * d2);
    }
    const int i0 = slice * 32;
    if (tid < 32) {
        int i = i0 + tid;
        if (i < NT) {
            float w0 = sA[i];
            float mean0 = sB[i] / (w0 + s);
            float d0 = mean0 - tm;
            sT0[tid] = w0 * (d0 * d0);
        }
    }
    __syncthreads();

    unsigned long long best = 0ull;
    if (tid < NT) {
        const float cb  = sA[tid];
        const float m1v = sB[tid];
        const float w2  = 1.0f - cb;
        const float t2v = sT2[tid];
#pragma unroll 8
        for (int il = 0; il < 32; ++il) {
            int i = i0 + il;
            if (i >= NT) break;
            float w0 = sA[i];
            float w1 = cb - w0;
            float mean1 = (m1v - sB[i]) / (w1 + s);
            float d1 = mean1 - tm;
            float bv = (sT0[il] + w1 * (d1 * d1)) + t2v;
            bool ok = (w0 > 0.f) && (w1 > 0.f) && (w2 > 0.f);
            bv = ok ? bv : 0.0f;
            unsigned k = (unsigned)(i * NT + tid);
            // bv >= 0: float-bit order == value order; ~k => first-max tie-break
            unsigned long long pk =
                ((unsigned long long)__float_as_uint(bv) << 32) | (0xFFFFFFFFu - k);
            best = pk > best ? pk : best;
        }
    }
    s_pack[tid] = best;
    __syncthreads();
    for (int off = 128; off > 0; off >>= 1) {
        if (tid < off) {
            unsigned long long o = s_pack[tid + off];
            if (o > s_pack[tid]) s_pack[tid] = o;
        }
        __syncthreads();
    }
    if (tid == 0) {
        packed_s[b * 8 + slice] = s_pack[0];    // plain store
        if (slice == 0) totf[b] = ftot;         // plain store
    }
}

// ---------------------------------------------------------------------------
// Kernel 3: per-batch loss eval (32 blocks, no polls). Combine 8 slice
// maxima, f64 suffix-sum loss (verbatim validated R5-R11 math).
// ---------------------------------------------------------------------------
__global__ __launch_bounds__(256) void k_eval(const int* __restrict__ g0_p,
                                              const float* __restrict__ g1_p,
                                              const float* __restrict__ p2_p,
                                              const unsigned long long* __restrict__ packed_s,
                                              const float* __restrict__ totf,
                                              float* __restrict__ lp) {
    __shared__ unsigned long long s_pack[8];
    __shared__ double sD0[256];
    __shared__ double sD1[256];
    __shared__ double s_res[4];
    __shared__ int    s_am;

    const int tid = threadIdx.x;
    const int b   = blockIdx.x;

    if (tid < 8) s_pack[tid] = packed_s[b * 8 + tid];
    __syncthreads();
    if (tid == 0) {
        unsigned long long best = s_pack[0];
#pragma unroll
        for (int j = 1; j < 8; ++j)
            if (s_pack[j] > best) best = s_pack[j];
        s_am = (int)(0xFFFFFFFFu - (unsigned)(best & 0xFFFFFFFFull));
    }
    __syncthreads();

    const int v  = s_am / NT + 1;           // im >= t1  <=>  q >= v
    const int wq = s_am % NT + 1;           // im >= t2  <=>  q >= wq

    // reduce g0/g1 partials for this batch
    int   gc = 0;
    float gg = 0.0f;
    {
        const int*   gp  = g0_p + ((b * 32) << 8) + tid;
        const float* gfp = g1_p + ((b * 32) << 8) + tid;
#pragma unroll 8
        for (int j = 0; j < 32; ++j) { gc += gp[j << 8]; gg += gfp[j << 8]; }
    }

    // f64 suffix sums S0/S1 at v and wq (validated R5-R11 math)
    sD0[tid] = (tid >= v) ? (double)gc : 0.0;
    sD1[tid] = (tid >= v) ? (double)gg : 0.0;
    __syncthreads();
    for (int off = 128; off > 0; off >>= 1) {
        if (tid < off) { sD0[tid] += sD0[tid + off]; sD1[tid] += sD1[tid + off]; }
        __syncthreads();
    }
    if (tid == 0) { s_res[0] = sD0[0]; s_res[1] = sD1[0]; }
    __syncthreads();

    sD0[tid] = (tid >= wq) ? (double)gc : 0.0;
    sD1[tid] = (tid >= wq) ? (double)gg : 0.0;
    __syncthreads();
    for (int off = 128; off > 0; off >>= 1) {
        if (tid < off) { sD0[tid] += sD0[tid + off]; sD1[tid] += sD1[tid + off]; }
        __syncthreads();
    }
    if (tid == 0) { s_res[2] = sD0[0]; s_res[3] = sD1[0]; }
    __syncthreads();

    // p2 partial reduce (32 values)
    sD0[tid] = (tid < 32) ? (double)p2_p[b * 32 + tid] : 0.0;
    __syncthreads();
    for (int off = 128; off > 0; off >>= 1) {
        if (tid < off) sD0[tid] += sD0[tid + off];
        __syncthreads();
    }

    if (tid == 0) {
        double S0v = s_res[0], S1v = s_res[1];
        double S0w = s_res[2], S1w = s_res[3];
        double c05 = (v <= wq) ? (S0v - S0w) : 0.0;
        double s05 = (v <= wq) ? (S1v - S1w) : 0.0;
        // sum (ci-p)^2 = |A| - 2*S1(A) + 0.25*|B\A| - S1(B\A) + sum p^2
        double sqd = S0w - 2.0 * S1w + 0.25 * c05 - s05 + sD0[0];
        float smv = totf[b] + 1e-8f;
        lp[b] = (smv > 1e-8f) ? (float)sqd / smv : 0.0f;    // plain store
    }
}

// ---------------------------------------------------------------------------
// Kernel 4: final valid-batch mean (1 block, plain loads).
// ---------------------------------------------------------------------------
__global__ __launch_bounds__(64) void k_final(const float* __restrict__ lp,
                                              const float* __restrict__ totf,
                                              float* __restrict__ out) {
    int t = threadIdx.x;
    float l = 0.0f, vc = 0.0f;
    if (t < B_) {
        float smv = totf[t] + 1e-8f;
        if (smv > 1e-8f) { l = lp[t]; vc = 1.0f; }
    }
    for (int off = 32; off > 0; off >>= 1) {
        l  += __shfl_down(l, off);
        vc += __shfl_down(vc, off);
    }
    if (t == 0) out[0] = vc > 0.0f ? l / fmaxf(vc, 1.0f) : 0.0f;
}

extern "C" void kernel_launch(void* const* d_in, const int* in_sizes, int n_in,
                              void* d_out, int out_size, void* d_ws, size_t ws_size,
                              hipStream_t stream) {
    const float* preds  = (const float*)d_in[0];
    const float* labels = (const float*)d_in[1];
    const float* images = (const float*)d_in[2];
    float* out = (float*)d_out;
    char* ws = (char*)d_ws;
    if (ws_size < (size_t)WS_NEED) return;  // harness ws is ~268 MB; never hit

    int*                hist_p   = (int*)ws;
    int*                g0_p     = (int*)(ws + 1048576);
    float*              g1_p     = (float*)(ws + 2097152);
    float*              p2_p     = (float*)(ws + 3145728);
    unsigned long long* packed_s = (unsigned long long*)(ws + 3149824);
    float*              totf     = (float*)(ws + 3151872);
    float*              lp       = (float*)(ws + 3152000);

    k_main_p<<<dim3(32, B_), 256, 0, stream>>>(labels, images, preds,
                                               hist_p, g0_p, g1_p, p2_p);
    k_search_s<<<256, 256, 0, stream>>>(hist_p, packed_s, totf);
    k_eval<<<B_, 256, 0, stream>>>(g0_p, g1_p, p2_p, packed_s, totf, lp);
    k_final<<<1, 64, 0, stream>>>(lp, totf, out);
}

// Round 13
// 140.853 us; speedup vs baseline: 1.1961x; 1.0012x over previous
//
#include <hip/hip_runtime.h>
#include <math.h>

#define B_    32
#define H_    512
#define W_    512
#define NBINS 256
#define NT    254
#define HW_   (H_ * W_)

// ws layout — every slot written unconditionally this launch; cross-dispatch
// readers rely on kernel-boundary coherence. The only intra-dispatch
// communication is k_eval's one-shot ticket (R2/R4-validated, no spin).
//   [0       .. 1048576)  int   hist_p[1024][256]   per-block Otsu-hist partial
//   [1048576 .. 2097152)  int   g0_p[1024][256]     per-block q-bucket count
//   [2097152 .. 3145728)  float g1_p[1024][256]     per-block q-bucket sum-p
//   [3145728 .. 3149824)  float p2_p[1024]          per-block sum p^2
//   [3149824 .. 3151872)  ull   packed_s[32][8]     per-slice argmax
//   [3151872 .. 3152000)  float totf[32]            per-batch mask count
//   [3152000 .. 3152128)  float lp[32]              per-batch loss
//   [3152128 .. 3152132)  int   ticket              zeroed by k_search_s
#define WS_NEED 3152132

__device__ __forceinline__ float max5(float a, float b, float c, float d, float e) {
    return fmaxf(fmaxf(fmaxf(a, b), fmaxf(c, d)), e);
}
__device__ __forceinline__ float4 fmax4(float4 a, float4 b) {
    return make_float4(fmaxf(a.x, b.x), fmaxf(a.y, b.y),
                       fmaxf(a.z, b.z), fmaxf(a.w, b.w));
}
__device__ __forceinline__ int bin_of(float im) {
    float v = im * 255.0f;                  // reference: v = imgs*255
    float u = v * (256.0f / 255.0f);        // reference: v*(NBINS/255.0) in f32
    int bin = (int)floorf(u);
    return bin < 0 ? 0 : (bin > NBINS - 1 ? NBINS - 1 : bin);
}

// Dilated-mask (5x5 max > 0) for 4 rows x 8 cols. Validated R7-R12.
__device__ __forceinline__ void dilate4(const float* __restrict__ lab,
                                        int rbase, int c0, int lane,
                                        unsigned mrow[4]) {
    float4 A[4], Bq[4];
#pragma unroll
    for (int r = 0; r < 4; ++r) {
        A[r]  = make_float4(0.f, 0.f, 0.f, 0.f);
        Bq[r] = A[r];
    }
#pragma unroll
    for (int k = 0; k < 8; ++k) {
        int gr = rbase - 2 + k;
        float4 la = make_float4(0.f, 0.f, 0.f, 0.f), lb = la;
        if ((unsigned)gr < (unsigned)H_) {
            la = *(const float4*)(lab + gr * W_ + c0);
            lb = *(const float4*)(lab + gr * W_ + c0 + 4);
        }
#pragma unroll
        for (int r = 0; r < 4; ++r)
            if (k >= r && k <= r + 4) { A[r] = fmax4(A[r], la); Bq[r] = fmax4(Bq[r], lb); }
    }
#pragma unroll
    for (int r = 0; r < 4; ++r) {
        float l2 = __shfl_up(Bq[r].z, 1);
        float l1 = __shfl_up(Bq[r].w, 1);
        float r1 = __shfl_down(A[r].x, 1);
        float r2 = __shfl_down(A[r].y, 1);
        if (lane == 0)  { l1 = 0.f; l2 = 0.f; }
        if (lane == 63) { r1 = 0.f; r2 = 0.f; }
        float e[12] = { l2, l1, A[r].x, A[r].y, A[r].z, A[r].w,
                        Bq[r].x, Bq[r].y, Bq[r].z, Bq[r].w, r1, r2 };
        unsigned m = 0;
#pragma unroll
        for (int c = 0; c < 8; ++c)
            if (max5(e[c], e[c+1], e[c+2], e[c+3], e[c+4]) > 0.f) m |= 1u << c;
        mrow[r] = m;
    }
}

// Per-pixel accumulate (validated R5-R12): Otsu hist + exact q-bucket + sum p^2.
__device__ __forceinline__ void px_acc(unsigned m, unsigned bit, float im, float p,
                                       int* s_hist, int* s_g0, float* s_g1,
                                       const float* s_thr, float& p2a) {
    if (m & bit) {
        atomicAdd(&s_hist[bin_of(im)], 1);
        int q0 = (int)(im * 255.0f);
        if (q0 > 254) q0 = 254;
        int q = q0;
        if (q0 < 254 && im >= s_thr[q0 + 1]) q = q0 + 1;
        else if (q0 > 0 && im < s_thr[q0])   q = q0 - 1;
        atomicAdd(&s_g0[q], 1);
        atomicAdd(&s_g1[q], p);
        p2a += p * p;
    }
}

// ---------------------------------------------------------------------------
// Kernel 1: dense single pass (R8/R12 best config, verbatim). 1024 blocks.
// ---------------------------------------------------------------------------
__global__ __launch_bounds__(256, 4) void k_main_p(const float* __restrict__ labels,
                                                   const float* __restrict__ images,
                                                   const float* __restrict__ preds,
                                                   int* __restrict__ hist_p,
                                                   int* __restrict__ g0_p,
                                                   float* __restrict__ g1_p,
                                                   float* __restrict__ p2_p) {
    __shared__ int   s_hist[NBINS];
    __shared__ int   s_g0[NBINS];
    __shared__ float s_g1[NBINS];
    __shared__ float s_thr[NBINS];
    __shared__ float s_red[256];

    const int tid   = threadIdx.x;
    const int lane  = tid & 63;
    const int w     = tid >> 6;
    const int band  = blockIdx.x;           // 0..31 (16-row bands)
    const int b     = blockIdx.y;           // 0..31
    const int slot  = b * 32 + band;
    const int rbase = band * 16 + w * 4;
    const int c0    = lane * 8;
    const float* lab = labels + (size_t)b * HW_;
    const float* img = images + (size_t)b * HW_;
    const float* prd = preds  + (size_t)b * HW_;

    s_hist[tid] = 0;
    s_g0[tid]   = 0;
    s_g1[tid]   = 0.0f;
    s_thr[tid]  = (float)tid / 255.0f;
    __syncthreads();

    unsigned mrow[4];
    dilate4(lab, rbase, c0, lane, mrow);

    float p2a = 0.0f;
#pragma unroll
    for (int r = 0; r < 4; ++r) {
        unsigned m = mrow[r];
        size_t off = (size_t)(rbase + r) * W_ + c0;
        // dense unconditional loads (sparse-load MLP collapse measured R4)
        float4 iv0 = *(const float4*)(img + off);
        float4 iv1 = *(const float4*)(img + off + 4);
        float4 pv0 = *(const float4*)(prd + off);
        float4 pv1 = *(const float4*)(prd + off + 4);
        px_acc(m,   1u, iv0.x, pv0.x, s_hist, s_g0, s_g1, s_thr, p2a);
        px_acc(m,   2u, iv0.y, pv0.y, s_hist, s_g0, s_g1, s_thr, p2a);
        px_acc(m,   4u, iv0.z, pv0.z, s_hist, s_g0, s_g1, s_thr, p2a);
        px_acc(m,   8u, iv0.w, pv0.w, s_hist, s_g0, s_g1, s_thr, p2a);
        px_acc(m,  16u, iv1.x, pv1.x, s_hist, s_g0, s_g1, s_thr, p2a);
        px_acc(m,  32u, iv1.y, pv1.y, s_hist, s_g0, s_g1, s_thr, p2a);
        px_acc(m,  64u, iv1.z, pv1.z, s_hist, s_g0, s_g1, s_thr, p2a);
        px_acc(m, 128u, iv1.w, pv1.w, s_hist, s_g0, s_g1, s_thr, p2a);
    }

    s_red[tid] = p2a;
    __syncthreads();
    // plain stores to this block's own slot (every slot written -> poison-safe)
    hist_p[(slot << 8) + tid] = s_hist[tid];
    g0_p  [(slot << 8) + tid] = s_g0[tid];
    g1_p  [(slot << 8) + tid] = s_g1[tid];
    for (int off = 128; off > 0; off >>= 1) {
        if (tid < off) s_red[tid] += s_red[tid + off];
        __syncthreads();
    }
    if (tid == 0) p2_p[slot] = s_red[0];
}

// ---------------------------------------------------------------------------
// Kernel 2: sliced Otsu argmax, NO polls (R12 verbatim + ticket zeroing).
// 256 blocks = 8 i-slices x 32 batches; 32-iter inner loop.
// ---------------------------------------------------------------------------
__global__ __launch_bounds__(256) void k_search_s(const int* __restrict__ hist_p,
                                                  unsigned long long* __restrict__ packed_s,
                                                  float* __restrict__ totf,
                                                  int* __restrict__ ticket) {
    __shared__ float  sA[NBINS];
    __shared__ float  sB[NBINS];
    __shared__ float  sPQ[NBINS][2];
    __shared__ float  sT0[32];
    __shared__ float  sT2[NBINS];
    __shared__ int    s_int[256];
    __shared__ unsigned long long s_pack[256];

    const int tid   = threadIdx.x;
    const int slice = blockIdx.x & 7;
    const int b     = blockIdx.x >> 3;
    const float s   = 1e-8f;

    if (blockIdx.x == 0 && tid == 0) *ticket = 0;   // published at kernel end

    // reduce 32 band-partials -> this batch's histogram bin `tid`
    int h = 0;
    {
        const int* hp = hist_p + ((b * 32) << 8) + tid;
#pragma unroll 8
        for (int j = 0; j < 32; ++j) h += hp[j << 8];
    }
    s_int[tid] = h;
    __syncthreads();
    for (int off = 128; off > 0; off >>= 1) {       // exact: integer counts
        if (tid < off) s_int[tid] += s_int[tid + off];
        __syncthreads();
    }
    const float ftot = (float)s_int[0];
    __syncthreads();

    float p = (float)h / ftot;
    sPQ[tid][0] = p;
    sPQ[tid][1] = p * (float)tid;
    __syncthreads();

    if (tid == 0) {                  // sequential fold == reference cumsum order
        float ch = 0.0f, cm = 0.0f;
#pragma unroll 8
        for (int i = 0; i < NBINS; ++i) {
            ch += sPQ[i][0];
            cm += sPQ[i][1];
            sA[i] = ch;
            sB[i] = cm;
        }
    }
    __syncthreads();

    const float tm = sB[NBINS - 1];
    if (tid < NT) {
        float cb = sA[tid];
        float w2 = 1.0f - cb;
        float mean2 = (tm - sB[tid]) / (w2 + s);
        float d2 = mean2 - tm;
        sT2[tid] = w2 * (d2 * d2);
    }
    const int i0 = slice * 32;
    if (tid < 32) {
        int i = i0 + tid;
        if (i < NT) {
            float w0 = sA[i];
            float mean0 = sB[i] / (w0 + s);
            float d0 = mean0 - tm;
            sT0[tid] = w0 * (d0 * d0);
        }
    }
    __syncthreads();

    unsigned long long best = 0ull;
    if (tid < NT) {
        const float cb  = sA[tid];
        const float m1v = sB[tid];
        const float w2  = 1.0f - cb;
        const float t2v = sT2[tid];
#pragma unroll 8
        for (int il = 0; il < 32; ++il) {
            int i = i0 + il;
            if (i >= NT) break;
            float w0 = sA[i];
            float w1 = cb - w0;
            float mean1 = (m1v - sB[i]) / (w1 + s);
            float d1 = mean1 - tm;
            float bv = (sT0[il] + w1 * (d1 * d1)) + t2v;
            bool ok = (w0 > 0.f) && (w1 > 0.f) && (w2 > 0.f);
            bv = ok ? bv : 0.0f;
            unsigned k = (unsigned)(i * NT + tid);
            // bv >= 0: float-bit order == value order; ~k => first-max tie-break
            unsigned long long pk =
                ((unsigned long long)__float_as_uint(bv) << 32) | (0xFFFFFFFFu - k);
            best = pk > best ? pk : best;
        }
    }
    s_pack[tid] = best;
    __syncthreads();
    for (int off = 128; off > 0; off >>= 1) {
        if (tid < off) {
            unsigned long long o = s_pack[tid + off];
            if (o > s_pack[tid]) s_pack[tid] = o;
        }
        __syncthreads();
    }
    if (tid == 0) {
        packed_s[b * 8 + slice] = s_pack[0];    // plain store
        if (slice == 0) totf[b] = ftot;         // plain store
    }
}

// ---------------------------------------------------------------------------
// Kernel 3: per-batch loss eval (32 blocks) + fused final mean via one-shot
// ticket (R2/R4-validated pattern: atomicAdd + threadfence, no spinning).
// ---------------------------------------------------------------------------
__global__ __launch_bounds__(256) void k_eval(const int* __restrict__ g0_p,
                                              const float* __restrict__ g1_p,
                                              const float* __restrict__ p2_p,
                                              const unsigned long long* __restrict__ packed_s,
                                              const float* __restrict__ totf,
                                              float* __restrict__ lp,
                                              int* __restrict__ ticket,
                                              float* __restrict__ out) {
    __shared__ unsigned long long s_pack[8];
    __shared__ double sD0[256];
    __shared__ double sD1[256];
    __shared__ double s_res[4];
    __shared__ int    s_am;

    const int tid = threadIdx.x;
    const int b   = blockIdx.x;

    if (tid < 8) s_pack[tid] = packed_s[b * 8 + tid];
    __syncthreads();
    if (tid == 0) {
        unsigned long long best = s_pack[0];
#pragma unroll
        for (int j = 1; j < 8; ++j)
            if (s_pack[j] > best) best = s_pack[j];
        s_am = (int)(0xFFFFFFFFu - (unsigned)(best & 0xFFFFFFFFull));
    }
    __syncthreads();

    const int v  = s_am / NT + 1;           // im >= t1  <=>  q >= v
    const int wq = s_am % NT + 1;           // im >= t2  <=>  q >= wq

    // reduce g0/g1 partials for this batch
    int   gc = 0;
    float gg = 0.0f;
    {
        const int*   gp  = g0_p + ((b * 32) << 8) + tid;
        const float* gfp = g1_p + ((b * 32) << 8) + tid;
#pragma unroll 8
        for (int j = 0; j < 32; ++j) { gc += gp[j << 8]; gg += gfp[j << 8]; }
    }

    // f64 suffix sums S0/S1 at v and wq (validated R5-R12 math)
    sD0[tid] = (tid >= v) ? (double)gc : 0.0;
    sD1[tid] = (tid >= v) ? (double)gg : 0.0;
    __syncthreads();
    for (int off = 128; off > 0; off >>= 1) {
        if (tid < off) { sD0[tid] += sD0[tid + off]; sD1[tid] += sD1[tid + off]; }
        __syncthreads();
    }
    if (tid == 0) { s_res[0] = sD0[0]; s_res[1] = sD1[0]; }
    __syncthreads();

    sD0[tid] = (tid >= wq) ? (double)gc : 0.0;
    sD1[tid] = (tid >= wq) ? (double)gg : 0.0;
    __syncthreads();
    for (int off = 128; off > 0; off >>= 1) {
        if (tid < off) { sD0[tid] += sD0[tid + off]; sD1[tid] += sD1[tid + off]; }
        __syncthreads();
    }
    if (tid == 0) { s_res[2] = sD0[0]; s_res[3] = sD1[0]; }
    __syncthreads();

    // p2 partial reduce (32 values)
    sD0[tid] = (tid < 32) ? (double)p2_p[b * 32 + tid] : 0.0;
    __syncthreads();
    for (int off = 128; off > 0; off >>= 1) {
        if (tid < off) sD0[tid] += sD0[tid + off];
        __syncthreads();
    }

    if (tid == 0) {
        double S0v = s_res[0], S1v = s_res[1];
        double S0w = s_res[2], S1w = s_res[3];
        double c05 = (v <= wq) ? (S0v - S0w) : 0.0;
        double s05 = (v <= wq) ? (S1v - S1w) : 0.0;
        // sum (ci-p)^2 = |A| - 2*S1(A) + 0.25*|B\A| - S1(B\A) + sum p^2
        double sqd = S0w - 2.0 * S1w + 0.25 * c05 - s05 + sD0[0];
        float smv = totf[b] + 1e-8f;
        float lpv = (smv > 1e-8f) ? (float)sqd / smv : 0.0f;
        __hip_atomic_store(&lp[b], lpv, __ATOMIC_RELEASE, __HIP_MEMORY_SCOPE_AGENT);
        __threadfence();
        int t = atomicAdd(ticket, 1);       // one-shot, no spin
        if (t == B_ - 1) {                  // last block: all lp[] published
            __threadfence();
            float sum = 0.0f;
            int   cnt = 0;
            for (int bb = 0; bb < B_; ++bb) {   // linear order == reference
                float tt = totf[bb];
                float ll = __hip_atomic_load(&lp[bb], __ATOMIC_RELAXED,
                                             __HIP_MEMORY_SCOPE_AGENT);
                if (tt + 1e-8f > 1e-8f) { sum += ll; cnt += 1; }
            }
            out[0] = cnt > 0 ? sum / fmaxf((float)cnt, 1.0f) : 0.0f;
        }
    }
}

extern "C" void kernel_launch(void* const* d_in, const int* in_sizes, int n_in,
                              void* d_out, int out_size, void* d_ws, size_t ws_size,
                              hipStream_t stream) {
    const float* preds  = (const float*)d_in[0];
    const float* labels = (const float*)d_in[1];
    const float* images = (const float*)d_in[2];
    float* out = (float*)d_out;
    char* ws = (char*)d_ws;
    if (ws_size < (size_t)WS_NEED) return;  // harness ws is ~268 MB; never hit

    int*                hist_p   = (int*)ws;
    int*                g0_p     = (int*)(ws + 1048576);
    float*              g1_p     = (float*)(ws + 2097152);
    float*              p2_p     = (float*)(ws + 3145728);
    unsigned long long* packed_s = (unsigned long long*)(ws + 3149824);
    float*              totf     = (float*)(ws + 3151872);
    float*              lp       = (float*)(ws + 3152000);
    int*                ticket   = (int*)(ws + 3152128);

    k_main_p<<<dim3(32, B_), 256, 0, stream>>>(labels, images, preds,
                                               hist_p, g0_p, g1_p, p2_p);
    k_search_s<<<256, 256, 0, stream>>>(hist_p, packed_s, totf, ticket);
    k_eval<<<B_, 256, 0, stream>>>(g0_p, g1_p, p2_p, packed_s, totf,
                                   lp, ticket, out);
}